// Round 7
// baseline (1663.718 us; speedup 1.0000x reference)
//
#include <hip/hip_runtime.h>

#define DDIM 1024
#define FDIM 4096
#define NEXP 8
#define BT   64      // tokens per tile
#define FC   128     // F chunk
#define WOFF (1u << 20)   // weight area offset in d_ws (routing lives below)

typedef __attribute__((ext_vector_type(8))) short bf16x8;
typedef __attribute__((ext_vector_type(4))) float f32x4;

__device__ __forceinline__ unsigned short f2bf(float f) {
  unsigned int u = __float_as_uint(f);
  u += 0x7fffu + ((u >> 16) & 1u);
  return (unsigned short)(u >> 16);
}

// ---------------- gating: top-2 + softmax + routing lists ----------------
__launch_bounds__(64)
__global__ void gate_kernel(const float* __restrict__ x, const float* __restrict__ Wg,
                            const float* __restrict__ bg,
                            int* __restrict__ cnt, int* __restrict__ tlist,
                            float* __restrict__ wlist, int nTok) {
  const int t = blockIdx.x;
  const int l = threadIdx.x;
  const float* xr = x + (size_t)t * DDIM;
  float acc[NEXP];
  #pragma unroll
  for (int e = 0; e < NEXP; ++e) acc[e] = 0.f;
  for (int d = l; d < DDIM; d += 64) {
    float xv = xr[d];
    const float* wr = Wg + d * NEXP;
    #pragma unroll
    for (int e = 0; e < NEXP; ++e) acc[e] += xv * wr[e];
  }
  #pragma unroll
  for (int e = 0; e < NEXP; ++e) {
    #pragma unroll
    for (int off = 32; off > 0; off >>= 1) acc[e] += __shfl_down(acc[e], off);
  }
  if (l == 0) {
    const float scale = 1.0f / (1.0f + 1e-6f);
    float g[NEXP];
    #pragma unroll
    for (int e = 0; e < NEXP; ++e) g[e] = (acc[e] + bg[e]) * scale;
    int i0 = 0;
    #pragma unroll
    for (int e = 1; e < NEXP; ++e) if (g[e] > g[i0]) i0 = e;
    int i1 = -1;
    #pragma unroll
    for (int e = 0; e < NEXP; ++e) {
      if (e == i0) continue;
      if (i1 < 0 || g[e] > g[i1]) i1 = e;
    }
    float p  = expf(g[i1] - g[i0]);     // g[i1] <= g[i0] -> p in (0,1]
    float w0 = 1.f / (1.f + p);
    float w1 = 1.f - w0;
    int p0 = atomicAdd(&cnt[i0], 1);
    tlist[i0 * nTok + p0] = t; wlist[i0 * nTok + p0] = w0;
    int p1 = atomicAdd(&cnt[i1], 1);
    tlist[i1 * nTok + p1] = t; wlist[i1 * nTok + p1] = w1;
  }
}

// ---------------- fp32 [E][R][C] -> bf16 transposed [E][C][R] ----------------
__launch_bounds__(256)
__global__ void conv_t(const float* __restrict__ in, unsigned short* __restrict__ out,
                       int R, int C) {
  __shared__ unsigned short t[64][65];
  const int e  = blockIdx.z;
  const int r0 = blockIdx.y * 64;
  const int c0 = blockIdx.x * 64;
  const float* ine = in + (size_t)e * R * C;
  unsigned short* oute = out + (size_t)e * R * C;
  const int tid = threadIdx.x;
  const int r = tid >> 2, g = tid & 3;
  #pragma unroll
  for (int i = 0; i < 4; ++i) {
    float4 v = *(const float4*)(ine + (size_t)(r0 + r) * C + c0 + g * 16 + i * 4);
    t[r][g * 16 + i * 4 + 0] = f2bf(v.x);
    t[r][g * 16 + i * 4 + 1] = f2bf(v.y);
    t[r][g * 16 + i * 4 + 2] = f2bf(v.z);
    t[r][g * 16 + i * 4 + 3] = f2bf(v.w);
  }
  __syncthreads();
  unsigned short buf[16];
  #pragma unroll
  for (int j = 0; j < 16; ++j) buf[j] = t[g * 16 + j][r];
  unsigned short* op = oute + (size_t)(c0 + r) * R + r0 + g * 16;
  *(bf16x8*)(op)     = *(bf16x8*)&buf[0];
  *(bf16x8*)(op + 8) = *(bf16x8*)&buf[8];
}

// ---------------- fused routed MLP: silu(xW1+b1)W2+b2, weighted scatter ----------------
// PRE=true: weights come from bf16 transposed copies W1T [e][f][d], W2T [e][d][f].
// PRE=false: weights read strided from original fp32 tensors (fallback).
template<bool PRE>
__launch_bounds__(512)
__global__ void moe_mlp(const float* __restrict__ x,
                        const float* __restrict__ W1, const float* __restrict__ b1,
                        const float* __restrict__ W2, const float* __restrict__ b2,
                        const unsigned short* __restrict__ W1T,
                        const unsigned short* __restrict__ W2T,
                        const int* __restrict__ cnt, const int* __restrict__ tlist,
                        const float* __restrict__ wlist, float* __restrict__ out,
                        int nTok, int tilesPerE) {
  __shared__ short xs[BT * DDIM];   // 128 KB, XOR-swizzled rows
  __shared__ short hs[BT * FC];     // 16 KB, XOR-swizzled rows
  __shared__ int   tok_s[BT];
  __shared__ float wt_s[BT];

  const int bx   = blockIdx.x;
  const int e    = bx / tilesPerE;
  const int tile = bx - e * tilesPerE;
  const int base = tile * BT;
  const int c_e  = cnt[e];
  if (base >= c_e) return;
  int m = c_e - base; if (m > BT) m = BT;

  const int tid = threadIdx.x;
  if (tid < BT) {
    int tok = 0; float wt = 0.f;
    if (tid < m) {
      tok = tlist[e * nTok + base + tid];
      wt  = wlist[e * nTok + base + tid];
    }
    tok_s[tid] = tok; wt_s[tid] = wt;
  }
  __syncthreads();

  // stage x tile -> LDS bf16 (8 threads per row, 16B swizzled writes)
  {
    const int r = tid >> 3, j = tid & 7;
    const float* xr = x + (size_t)tok_s[r] * DDIM + j * 128;
    const int swz = (r & 7) << 3;  // in shorts
    #pragma unroll
    for (int i = 0; i < 16; ++i) {
      float4 f0 = *(const float4*)(xr + i * 8);
      float4 f1 = *(const float4*)(xr + i * 8 + 4);
      bf16x8 v;
      v[0] = (short)f2bf(f0.x); v[1] = (short)f2bf(f0.y);
      v[2] = (short)f2bf(f0.z); v[3] = (short)f2bf(f0.w);
      v[4] = (short)f2bf(f1.x); v[5] = (short)f2bf(f1.y);
      v[6] = (short)f2bf(f1.z); v[7] = (short)f2bf(f1.w);
      const int d = j * 128 + i * 8;
      *(bf16x8*)&xs[r * DDIM + (d ^ swz)] = v;
    }
  }
  __syncthreads();

  const int w   = tid >> 6;   // wave 0..7
  const int l   = tid & 63;
  const int l15 = l & 15, l4 = l >> 4;

  const float* W1e = W1 + (size_t)e * DDIM * FDIM;
  const float* W2e = W2 + (size_t)e * FDIM * DDIM;
  const float* b1e = b1 + e * FDIM;
  const float* b2e = b2 + e * DDIM;

  f32x4 acc[4][8];
  #pragma unroll
  for (int a = 0; a < 4; ++a)
    #pragma unroll
    for (int b = 0; b < 8; ++b) acc[a][b] = (f32x4){0.f, 0.f, 0.f, 0.f};

  for (int c = 0; c < FDIM / FC; ++c) {
    const int f0 = c * FC;
    // ---- phase 1: h[64][128], this wave computes cols w*16..w*16+15, K=1024
    f32x4 hacc[4];
    #pragma unroll
    for (int a = 0; a < 4; ++a) hacc[a] = (f32x4){0.f, 0.f, 0.f, 0.f};
    const int fcol = f0 + w * 16 + l15;
    const float* W1c = W1e + fcol;                                   // fallback
    const unsigned short* W1tc = W1T + ((size_t)e * FDIM + fcol) * DDIM; // PRE

    #pragma unroll 4
    for (int kk = 0; kk < 32; ++kk) {
      const int k0 = kk * 32 + l4 * 8;
      bf16x8 bfr;
      if constexpr (PRE) {
        bfr = *(const bf16x8*)(W1tc + k0);
      } else {
        #pragma unroll
        for (int j = 0; j < 8; ++j) bfr[j] = (short)f2bf(W1c[(size_t)(k0 + j) * FDIM]);
      }
      #pragma unroll
      for (int mi = 0; mi < 4; ++mi) {
        const int r = mi * 16 + l15;
        const bf16x8 af = *(const bf16x8*)&xs[r * DDIM + (k0 ^ ((r & 7) << 3))];
        hacc[mi] = __builtin_amdgcn_mfma_f32_16x16x32_bf16(af, bfr, hacc[mi], 0, 0, 0);
      }
    }
    // bias + silu + write h to LDS (swizzled)
    const float b1v = b1e[fcol];
    const int hcol = w * 16 + l15;
    #pragma unroll
    for (int mi = 0; mi < 4; ++mi) {
      #pragma unroll
      for (int ri = 0; ri < 4; ++ri) {
        const int r = mi * 16 + l4 * 4 + ri;
        float v = hacc[mi][ri] + b1v;
        v = v / (1.f + __expf(-v));          // silu
        hs[r * FC + (hcol ^ ((r & 7) << 3))] = (short)f2bf(v);
      }
    }
    __syncthreads();

    // ---- phase 2: out[64][1024] += h * W2[f0:f0+128, :]; wave owns cols w*128..+127
    #pragma unroll
    for (int kk = 0; kk < 4; ++kk) {
      const int k0 = kk * 32 + l4 * 8;
      bf16x8 ha[4];
      #pragma unroll
      for (int mi = 0; mi < 4; ++mi) {
        const int r = mi * 16 + l15;
        ha[mi] = *(const bf16x8*)&hs[r * FC + (k0 ^ ((r & 7) << 3))];
      }
      const int fb = f0 + k0;
      #pragma unroll
      for (int nj = 0; nj < 8; ++nj) {
        const int dcol = w * 128 + nj * 16 + l15;
        bf16x8 bw;
        if constexpr (PRE) {
          bw = *(const bf16x8*)(W2T + ((size_t)e * DDIM + dcol) * FDIM + fb);
        } else {
          const float* W2c = W2e + dcol;
          #pragma unroll
          for (int j = 0; j < 8; ++j) bw[j] = (short)f2bf(W2c[(size_t)(fb + j) * DDIM]);
        }
        #pragma unroll
        for (int mi = 0; mi < 4; ++mi)
          acc[mi][nj] = __builtin_amdgcn_mfma_f32_16x16x32_bf16(ha[mi], bw, acc[mi][nj], 0, 0, 0);
      }
    }
    __syncthreads();
  }

  // ---- epilogue: + b2, * gate weight, atomic scatter
  #pragma unroll
  for (int mi = 0; mi < 4; ++mi) {
    #pragma unroll
    for (int ri = 0; ri < 4; ++ri) {
      const int r = mi * 16 + l4 * 4 + ri;
      if (r < m) {
        const float wt = wt_s[r];
        float* orow = out + (size_t)tok_s[r] * DDIM;
        #pragma unroll
        for (int nj = 0; nj < 8; ++nj) {
          const int dcol = w * 128 + nj * 16 + l15;
          atomicAdd(orow + dcol, (acc[mi][nj][ri] + b2e[dcol]) * wt);
        }
      }
    }
  }
}

extern "C" void kernel_launch(void* const* d_in, const int* in_sizes, int n_in,
                              void* d_out, int out_size, void* d_ws, size_t ws_size,
                              hipStream_t stream) {
  const float* x  = (const float*)d_in[0];
  const float* Wg = (const float*)d_in[1];
  const float* bg = (const float*)d_in[2];
  const float* W1 = (const float*)d_in[3];
  const float* b1 = (const float*)d_in[4];
  const float* W2 = (const float*)d_in[5];
  const float* b2 = (const float*)d_in[6];
  float* out = (float*)d_out;

  const int nTok = in_sizes[0] / DDIM;   // 8192

  // workspace layout: [cnt | tlist | wlist | ... | W1T bf16 | W2T bf16]
  int*   cnt   = (int*)d_ws;                               // 8 ints
  int*   tlist = (int*)((char*)d_ws + 256);                // E*nTok ints
  float* wlist = (float*)((char*)d_ws + 256 + (size_t)NEXP * nTok * 4);

  const size_t wElems = (size_t)NEXP * DDIM * FDIM;        // 33.55M per tensor
  unsigned short* W1T = (unsigned short*)((char*)d_ws + WOFF);
  unsigned short* W2T = W1T + wElems;
  const size_t need = (size_t)WOFF + 2 * wElems * sizeof(unsigned short);
  const bool pre = ws_size >= need;

  hipMemsetAsync(d_out, 0, (size_t)out_size * sizeof(float), stream);
  hipMemsetAsync(cnt, 0, NEXP * sizeof(int), stream);

  gate_kernel<<<nTok, 64, 0, stream>>>(x, Wg, bg, cnt, tlist, wlist, nTok);

  const int tilesPerE = (nTok + BT - 1) / BT;              // 128

  if (pre) {
    // W1 [E][1024][4096] -> W1T [E][4096][1024]; W2 [E][4096][1024] -> W2T [E][1024][4096]
    conv_t<<<dim3(FDIM / 64, DDIM / 64, NEXP), 256, 0, stream>>>(W1, W1T, DDIM, FDIM);
    conv_t<<<dim3(DDIM / 64, FDIM / 64, NEXP), 256, 0, stream>>>(W2, W2T, FDIM, DDIM);
    moe_mlp<true><<<NEXP * tilesPerE, 512, 0, stream>>>(x, W1, b1, W2, b2, W1T, W2T,
                                                        cnt, tlist, wlist, out,
                                                        nTok, tilesPerE);
  } else {
    moe_mlp<false><<<NEXP * tilesPerE, 512, 0, stream>>>(x, W1, b1, W2, b2, W1T, W2T,
                                                         cnt, tlist, wlist, out,
                                                         nTok, tilesPerE);
  }
}